// Round 3
// baseline (2162.936 us; speedup 1.0000x reference)
//
#include <hip/hip_runtime.h>

// UniRNN T=512,B=256,X=H1=H2=256 fp32. Single cooperative launch, 4-stage
// producer-consumer pipeline (all stages overlap in time):
//   P (64 WGs): x1[t] = A[t] @ W_ih1^T + b_ih1      (split A, split W, fp32)
//   A (16 WGs): h1[t] = tanh(x1[t] + h1 @ W_hh1^T + b_hh1)   (scan, 3-pass)
//   B (32 WGs): u[t]  = h1[t] @ W_ih2^T + b_ih2 + b_hh2      (2-pass, ->d_out)
//   C (16 WGs): h2[t] = tanh(u[t] + h2 @ W_hh2^T)  (scan, 3-pass, in-place)
// Sync: agent-scope release/acquire flags per (mb,t); relaxed backpressure
// counters for the rolling x1/h1 windows (depth 64 steps).
// d_ws usage: 16MB x1 + 8MB h1 + 96KB flags  (<< 67MB known-available).

#define TT 512
#define BB 256
#define HH 256
#define LSTR 280
#define SP 4            // P WGs per batch-block
#define SB 2            // B WGs per batch-block
#define DX 64           // x1 rolling depth (steps)
#define DH 64           // h1 rolling depth (steps)
#define NP (16*SP)
#define NA 16
#define NB (16*SB)
#define NC 16
#define GRID (NP+NA+NB+NC)

typedef short bf16x8 __attribute__((ext_vector_type(8)));
typedef float f32x4  __attribute__((ext_vector_type(4)));

__device__ inline unsigned short f2bf(float f) {
    unsigned int u = __float_as_uint(f);
    u = u + 0x7fffu + ((u >> 16) & 1u);          // RNE
    return (unsigned short)(u >> 16);
}
__device__ inline float bf2f(unsigned short h) {
    return __uint_as_float(((unsigned int)h) << 16);
}
__device__ inline float tanh_fast(float x) {
    float e = __expf(2.0f * x);
    return 1.0f - 2.0f * __builtin_amdgcn_rcpf(e + 1.0f);
}
__device__ inline void split8(const float* __restrict__ p, bf16x8& hi, bf16x8& lo) {
    float4 v0 = ((const float4*)p)[0], v1 = ((const float4*)p)[1];
    float w[8] = {v0.x, v0.y, v0.z, v0.w, v1.x, v1.y, v1.z, v1.w};
#pragma unroll
    for (int i = 0; i < 8; ++i) {
        unsigned short h = f2bf(w[i]);
        hi[i] = (short)h;
        lo[i] = (short)f2bf(w[i] - bf2f(h));
    }
}
__device__ inline f32x4 mfma16(bf16x8 a, bf16x8 b, f32x4 c) {
    return __builtin_amdgcn_mfma_f32_16x16x32_bf16(a, b, c, 0, 0, 0);
}
__device__ inline unsigned ld_acq(unsigned* p) {
    return __hip_atomic_load(p, __ATOMIC_ACQUIRE, __HIP_MEMORY_SCOPE_AGENT);
}
__device__ inline unsigned ld_rlx(unsigned* p) {
    return __hip_atomic_load(p, __ATOMIC_RELAXED, __HIP_MEMORY_SCOPE_AGENT);
}
__device__ inline void st_rel(unsigned* p, unsigned v) {
    __hip_atomic_store(p, v, __ATOMIC_RELEASE, __HIP_MEMORY_SCOPE_AGENT);
}
__device__ inline void st_rlx(unsigned* p, unsigned v) {
    __hip_atomic_store(p, v, __ATOMIC_RELAXED, __HIP_MEMORY_SCOPE_AGENT);
}

struct Params {
    const float *A, *is1, *is2;
    const float *Wih1, *Whh1, *bih1, *bhh1, *Wih2, *Whh2, *bih2, *bhh2;
    float *out, *h1f, *h2f;
    float *x1buf;                 // [16][DX][16][256] fp32
    unsigned short *h1buf;        // [16][DH][16][256] bf16
    unsigned *flagP, *flagA, *flagB, *progA, *progBc;
};

__global__ __launch_bounds__(512, 2)
void rnn_pipe(Params p)
{
    __shared__ unsigned short hs_hi[2][16 * LSTR];
    __shared__ unsigned short hs_lo[2][16 * LSTR];

    const int gid  = blockIdx.x;
    const int tid  = threadIdx.x;
    const int lane = tid & 63, wv = tid >> 6;
    const int quad = lane >> 4, l15 = lane & 15;
    const int n0   = wv * 32;
    const int colb = n0 + l15;

    // =====================================================================
    if (gid < NP) {                       // ---- Stage P: x1 projection ----
        const int mb = gid & 15, s = gid >> 4;
        bf16x8 wh[2][8], wl[2][8];
        float  biasv[2];
#pragma unroll
        for (int nt = 0; nt < 2; ++nt) {
            int n = n0 + nt * 16 + l15;
            biasv[nt] = p.bih1[n];
#pragma unroll
            for (int kc = 0; kc < 8; ++kc)
                split8(p.Wih1 + (size_t)n * HH + kc * 32 + quad * 8, wh[nt][kc], wl[nt][kc]);
        }
        for (int t = s; t < TT; t += SP) {
            if (t >= DX) {                // rolling-buffer backpressure
                unsigned need = (unsigned)(t - DX + 1);
                while (ld_rlx(&p.progA[mb]) < need) __builtin_amdgcn_s_sleep(2);
            }
            const float* at = p.A + (((size_t)t * BB) + mb * 16 + l15) * HH;
            bf16x8 ah[8], al[8];
#pragma unroll
            for (int kc = 0; kc < 8; ++kc)
                split8(at + kc * 32 + quad * 8, ah[kc], al[kc]);

            f32x4 aA[2], aB[2], aC[2];
#pragma unroll
            for (int nt = 0; nt < 2; ++nt)
                aA[nt] = aB[nt] = aC[nt] = (f32x4){0.f, 0.f, 0.f, 0.f};
#pragma unroll
            for (int kc = 0; kc < 8; ++kc) {
#pragma unroll
                for (int nt = 0; nt < 2; ++nt) {
                    aA[nt] = mfma16(ah[kc], wh[nt][kc], aA[nt]);
                    aB[nt] = mfma16(al[kc], wh[nt][kc], aB[nt]);
                    aC[nt] = mfma16(ah[kc], wl[nt][kc], aC[nt]);
                }
            }
            float* xslot = p.x1buf + ((size_t)(mb * DX + (t & (DX - 1)))) * 4096;
#pragma unroll
            for (int nt = 0; nt < 2; ++nt)
#pragma unroll
                for (int r = 0; r < 4; ++r)
                    xslot[(quad * 4 + r) * 256 + colb + nt * 16] =
                        (aA[nt][r] + aB[nt][r]) + aC[nt][r] + biasv[nt];
            __syncthreads();              // drain stores (vmcnt0) before release
            if (tid == 0) st_rel(&p.flagP[mb * 512 + t], 1u);
        }
    }
    // =====================================================================
    else if (gid < NP + NA) {             // ---- Stage A: layer-1 scan ----
        const int mb = gid - NP;
        bf16x8 wh[2][8], wl[2][8];
        float  biasv[2];
#pragma unroll
        for (int nt = 0; nt < 2; ++nt) {
            int n = n0 + nt * 16 + l15;
            biasv[nt] = p.bhh1[n];
#pragma unroll
            for (int kc = 0; kc < 8; ++kc)
                split8(p.Whh1 + (size_t)n * HH + kc * 32 + quad * 8, wh[nt][kc], wl[nt][kc]);
        }
#pragma unroll
        for (int j = 0; j < 8; ++j) {
            int idx = tid + j * 512;
            int row = idx >> 8, col = idx & 255;
            float v = p.is1[(size_t)(mb * 16 + row) * HH + col];
            unsigned short h = f2bf(v);
            hs_hi[0][row * LSTR + col] = h;
            hs_lo[0][row * LSTR + col] = f2bf(v - bf2f(h));
        }
        __syncthreads();

        for (int t = 0; t < TT; ++t) {
            const int cur = t & 1, nxt = (t + 1) & 1;
            if (wv == 0) {                // wave0 acquires for the WG
                while (ld_acq(&p.flagP[mb * 512 + t]) == 0) __builtin_amdgcn_s_sleep(1);
                if (t >= DH) {            // h1 rolling backpressure
                    unsigned need = (unsigned)(t - DH + 1);
                    int s2 = (t - DH) & (SB - 1);
                    while (ld_rlx(&p.progBc[mb * SB + s2]) < need) __builtin_amdgcn_s_sleep(1);
                }
            }
            __syncthreads();

            const float* xs = p.x1buf + ((size_t)(mb * DX + (t & (DX - 1)))) * 4096;
            float xv[2][4];
#pragma unroll
            for (int nt = 0; nt < 2; ++nt)
#pragma unroll
                for (int r = 0; r < 4; ++r)
                    xv[nt][r] = xs[(quad * 4 + r) * 256 + colb + nt * 16];

            bf16x8 ah[8], al[8];
#pragma unroll
            for (int kc = 0; kc < 8; ++kc) {
                ah[kc] = *(const bf16x8*)&hs_hi[cur][l15 * LSTR + kc * 32 + quad * 8];
                al[kc] = *(const bf16x8*)&hs_lo[cur][l15 * LSTR + kc * 32 + quad * 8];
            }
            f32x4 aA[2], aB[2], aC[2];
#pragma unroll
            for (int nt = 0; nt < 2; ++nt)
                aA[nt] = aB[nt] = aC[nt] = (f32x4){0.f, 0.f, 0.f, 0.f};
#pragma unroll
            for (int kc = 0; kc < 8; ++kc) {
#pragma unroll
                for (int nt = 0; nt < 2; ++nt) {
                    aA[nt] = mfma16(ah[kc], wh[nt][kc], aA[nt]);
                    aB[nt] = mfma16(al[kc], wh[nt][kc], aB[nt]);
                    aC[nt] = mfma16(ah[kc], wl[nt][kc], aC[nt]);
                }
            }
            unsigned short* hslot = p.h1buf + ((size_t)(mb * DH + (t & (DH - 1)))) * 4096;
#pragma unroll
            for (int nt = 0; nt < 2; ++nt)
#pragma unroll
                for (int r = 0; r < 4; ++r) {
                    float pre = (aA[nt][r] + aB[nt][r]) + aC[nt][r] + xv[nt][r] + biasv[nt];
                    float h   = tanh_fast(pre);
                    unsigned short hb = f2bf(h);
                    int row = quad * 4 + r, col = colb + nt * 16;
                    hs_hi[nxt][row * LSTR + col] = hb;
                    hs_lo[nxt][row * LSTR + col] = f2bf(h - bf2f(hb));
                    hslot[row * 256 + col] = hb;
                    if (t == TT - 1) p.h1f[(size_t)(mb * 16 + row) * HH + col] = h;
                }
            __syncthreads();              // LDS state + h1 stores drained
            if (tid == 0) {
                st_rlx(&p.progA[mb], (unsigned)(t + 1));
                st_rel(&p.flagA[mb * 512 + t], 1u);
            }
        }
    }
    // =====================================================================
    else if (gid < NP + NA + NB) {        // ---- Stage B: u projection ----
        const int q = gid - (NP + NA);
        const int mb = q & 15, s = q >> 4;
        bf16x8 wh[2][8], wl[2][8];
        float  biasv[2];
#pragma unroll
        for (int nt = 0; nt < 2; ++nt) {
            int n = n0 + nt * 16 + l15;
            biasv[nt] = p.bih2[n] + p.bhh2[n];
#pragma unroll
            for (int kc = 0; kc < 8; ++kc)
                split8(p.Wih2 + (size_t)n * HH + kc * 32 + quad * 8, wh[nt][kc], wl[nt][kc]);
        }
        for (int t = s; t < TT; t += SB) {
            if (wv == 0) {
                while (ld_acq(&p.flagA[mb * 512 + t]) == 0) __builtin_amdgcn_s_sleep(1);
            }
            __syncthreads();
            const unsigned short* hslot =
                p.h1buf + ((size_t)(mb * DH + (t & (DH - 1)))) * 4096;
            bf16x8 hf[8];
#pragma unroll
            for (int kc = 0; kc < 8; ++kc)
                hf[kc] = *(const bf16x8*)(hslot + l15 * 256 + kc * 32 + quad * 8);

            f32x4 aA[2], aC[2];
#pragma unroll
            for (int nt = 0; nt < 2; ++nt)
                aA[nt] = aC[nt] = (f32x4){0.f, 0.f, 0.f, 0.f};
#pragma unroll
            for (int kc = 0; kc < 8; ++kc) {
#pragma unroll
                for (int nt = 0; nt < 2; ++nt) {
                    aA[nt] = mfma16(hf[kc], wh[nt][kc], aA[nt]);
                    aC[nt] = mfma16(hf[kc], wl[nt][kc], aC[nt]);
                }
            }
#pragma unroll
            for (int nt = 0; nt < 2; ++nt)
#pragma unroll
                for (int r = 0; r < 4; ++r) {
                    size_t row = (size_t)t * BB + mb * 16 + quad * 4 + r;
                    p.out[row * HH + colb + nt * 16] = aA[nt][r] + aC[nt][r] + biasv[nt];
                }
            __syncthreads();
            if (tid == 0) {
                st_rlx(&p.progBc[mb * SB + s], (unsigned)(t + 1));
                st_rel(&p.flagB[mb * 512 + t], 1u);
            }
        }
    }
    // =====================================================================
    else {                                // ---- Stage C: layer-2 scan ----
        const int mb = gid - (NP + NA + NB);
        bf16x8 wh[2][8], wl[2][8];
#pragma unroll
        for (int nt = 0; nt < 2; ++nt) {
            int n = n0 + nt * 16 + l15;
#pragma unroll
            for (int kc = 0; kc < 8; ++kc)
                split8(p.Whh2 + (size_t)n * HH + kc * 32 + quad * 8, wh[nt][kc], wl[nt][kc]);
        }
#pragma unroll
        for (int j = 0; j < 8; ++j) {
            int idx = tid + j * 512;
            int row = idx >> 8, col = idx & 255;
            float v = p.is2[(size_t)(mb * 16 + row) * HH + col];
            unsigned short h = f2bf(v);
            hs_hi[0][row * LSTR + col] = h;
            hs_lo[0][row * LSTR + col] = f2bf(v - bf2f(h));
        }
        __syncthreads();

        for (int t = 0; t < TT; ++t) {
            const int cur = t & 1, nxt = (t + 1) & 1;
            if (wv == 0) {
                while (ld_acq(&p.flagB[mb * 512 + t]) == 0) __builtin_amdgcn_s_sleep(1);
            }
            __syncthreads();

            float uv[2][4];
#pragma unroll
            for (int nt = 0; nt < 2; ++nt)
#pragma unroll
                for (int r = 0; r < 4; ++r)
                    uv[nt][r] = p.out[((size_t)t * BB + mb * 16 + quad * 4 + r) * HH
                                      + colb + nt * 16];

            bf16x8 ah[8], al[8];
#pragma unroll
            for (int kc = 0; kc < 8; ++kc) {
                ah[kc] = *(const bf16x8*)&hs_hi[cur][l15 * LSTR + kc * 32 + quad * 8];
                al[kc] = *(const bf16x8*)&hs_lo[cur][l15 * LSTR + kc * 32 + quad * 8];
            }
            f32x4 aA[2], aB[2], aC[2];
#pragma unroll
            for (int nt = 0; nt < 2; ++nt)
                aA[nt] = aB[nt] = aC[nt] = (f32x4){0.f, 0.f, 0.f, 0.f};
#pragma unroll
            for (int kc = 0; kc < 8; ++kc) {
#pragma unroll
                for (int nt = 0; nt < 2; ++nt) {
                    aA[nt] = mfma16(ah[kc], wh[nt][kc], aA[nt]);
                    aB[nt] = mfma16(al[kc], wh[nt][kc], aB[nt]);
                    aC[nt] = mfma16(ah[kc], wl[nt][kc], aC[nt]);
                }
            }
#pragma unroll
            for (int nt = 0; nt < 2; ++nt)
#pragma unroll
                for (int r = 0; r < 4; ++r) {
                    float pre = (aA[nt][r] + aB[nt][r]) + aC[nt][r] + uv[nt][r];
                    float h   = tanh_fast(pre);
                    unsigned short hb = f2bf(h);
                    int row = quad * 4 + r, col = colb + nt * 16;
                    hs_hi[nxt][row * LSTR + col] = hb;
                    hs_lo[nxt][row * LSTR + col] = f2bf(h - bf2f(hb));
                    p.out[((size_t)t * BB + mb * 16 + row) * HH + col] = h;  // final
                    if (t == TT - 1) p.h2f[(size_t)(mb * 16 + row) * HH + col] = h;
                }
            __syncthreads();
        }
    }
}

extern "C" void kernel_launch(void* const* d_in, const int* in_sizes, int n_in,
                              void* d_out, int out_size, void* d_ws, size_t ws_size,
                              hipStream_t stream)
{
    Params p;
    p.A    = (const float*)d_in[0];
    p.is1  = (const float*)d_in[1];
    p.is2  = (const float*)d_in[2];
    p.Wih1 = (const float*)d_in[3];
    p.Whh1 = (const float*)d_in[4];
    p.bih1 = (const float*)d_in[5];
    p.bhh1 = (const float*)d_in[6];
    p.Wih2 = (const float*)d_in[7];
    p.Whh2 = (const float*)d_in[8];
    p.bih2 = (const float*)d_in[9];
    p.bhh2 = (const float*)d_in[10];

    float* out = (float*)d_out;
    const size_t OUT0 = (size_t)TT * BB * HH;
    p.out = out;
    p.h1f = out + OUT0;
    p.h2f = out + OUT0 + (size_t)BB * HH;

    char* ws = (char*)d_ws;
    const size_t X1BYTES = (size_t)16 * DX * 4096 * 4;   // 16 MB
    const size_t H1BYTES = (size_t)16 * DH * 4096 * 2;   // 8 MB
    p.x1buf  = (float*)ws;
    p.h1buf  = (unsigned short*)(ws + X1BYTES);
    char* fl = ws + X1BYTES + H1BYTES;
    p.flagP  = (unsigned*)(fl);
    p.flagA  = (unsigned*)(fl + 32768);
    p.flagB  = (unsigned*)(fl + 65536);
    p.progA  = (unsigned*)(fl + 98304);
    p.progBc = (unsigned*)(fl + 98304 + 256);
    const size_t FLBYTES = 98304 + 512;

    hipMemsetAsync((void*)fl, 0, FLBYTES, stream);

    void* kargs[] = {&p};
    hipLaunchCooperativeKernel((const void*)rnn_pipe, dim3(GRID), dim3(512),
                               kargs, 0, stream);
}